// Round 11
// baseline (1954.282 us; speedup 1.0000x reference)
//
#include <hip/hip_runtime.h>
#include <hip/hip_bf16.h>

#define T_DIM 256
#define B_DIM 256
#define E_DIM 256
#define H_DIM 512
#define V_DIM 50257
#define BH    (B_DIM * H_DIM)          // elems per h slot
#define PRE_AHEAD 5                    // at step t, re-arm slot t+5
#define SENT  0x7F7F7F7Fu              // bf16 |h|<=1 can never be 0x7F7F

typedef __attribute__((ext_vector_type(8))) short short8;
typedef __attribute__((ext_vector_type(4))) float f32x4;
typedef __attribute__((ext_vector_type(4))) unsigned int uint4v;
typedef __attribute__((ext_vector_type(2))) unsigned int uint2v;

#define MFMA __builtin_amdgcn_mfma_f32_16x16x32_bf16

__device__ __forceinline__ unsigned short f2bf(float f) {
    union { float f; unsigned u; } v; v.f = f;
    unsigned r = v.u + 0x7FFFu + ((v.u >> 16) & 1u);
    return (unsigned short)(r >> 16);
}
__device__ __forceinline__ short cvt_bf(float f) { return (short)f2bf(f); }
__device__ __forceinline__ float sigmoidf_(float x) {
    return 1.0f / (1.0f + __expf(-x));
}
__device__ __forceinline__ float tanhf_(float x) {
    float xc = fminf(fmaxf(x, -15.0f), 15.0f);
    float e = __expf(2.0f * xc);
    return (e - 1.0f) / (e + 1.0f);
}

// All h traffic via MALL (sc0 sc1): placement-independent. Data carries its
// own readiness (sentinel); producers are WAIT-FREE, so deadlock is
// impossible by construction. Loads return in-flight; consume only after
// s_waitcnt vmcnt(0) + sched_barrier(0) (rule 18).
__device__ __forceinline__ short8 load16_mall(const unsigned short* p) {
    short8 r;
    asm volatile("global_load_dwordx4 %0, %1, off sc0 sc1"
                 : "=v"(r) : "v"(p) : "memory");
    return r;
}
__device__ __forceinline__ void store8_mall(unsigned short* p, uint2v v) {
    asm volatile("global_store_dwordx2 %0, %1, off sc0 sc1"
                 :: "v"(p), "v"(v) : "memory");
}
__device__ __forceinline__ bool frag_ready(short8 v) {
    union { short8 s; uint4v u; } c; c.s = v;
    return (c.u[0] != SENT) & (c.u[1] != SENT) & (c.u[2] != SENT) & (c.u[3] != SENT);
}

// One LSTM step (R8 protocol, reordered for overlap). xc = current step's x
// (f32, resident: drained by the PREVIOUS step's vmcnt(0)); xn = buffer the
// prefetch issued here fills for t+1. Static ping-pong (rule 20).
__device__ __forceinline__ void lstm_step(
    int t, f32x4 (&xc)[16], f32x4 (&xn)[16],
    const float* __restrict__ xrow,              // x + arow*E + lk*8
    unsigned short* __restrict__ hbuf,
    size_t hrow_off, size_t hsto_off,
    const unsigned short* __restrict__ lds_w, int lane,
    const f32x4& bi, const f32x4& bj, const f32x4& bf_, const f32x4& bo,
    f32x4& c_frag)
{
    // ---- 1. C++ x-prefetch for t+1 (issued first; "memory"-clobbered asm
    //         below cannot be hoisted above it, so it leads the VMEM queue) --
    {
        const int tn = (t + 1 < T_DIM) ? t + 1 : t;
        const float* xp = xrow + (size_t)tn * (B_DIM * E_DIM);
        #pragma unroll
        for (int k = 0; k < 8; ++k) {
            xn[2 * k]     = *(const f32x4*)(xp + k * 32);
            xn[2 * k + 1] = *(const f32x4*)(xp + k * 32 + 4);
        }
    }

    // ---- 2. asm sweep loads for h_t ----
    const unsigned short* hr = hbuf + (size_t)t * BH + hrow_off;
    short8 hfr[16];
    if (t > 0) {
        #pragma unroll
        for (int k = 0; k < 16; ++k)
            hfr[k] = load16_mall(hr + k * 32);
    }

    // ---- 3. x-part MFMA on resident xc (covers sweep + prefetch RTT) ----
    f32x4 a0 = {0.f,0.f,0.f,0.f}, a1 = a0, a2 = a0, a3 = a0;
    #pragma unroll
    for (int kt = 0; kt < 8; ++kt) {
        const f32x4 lo = xc[2 * kt];
        const f32x4 hi = xc[2 * kt + 1];
        short8 a;
        a[0]=cvt_bf(lo[0]); a[1]=cvt_bf(lo[1]); a[2]=cvt_bf(lo[2]); a[3]=cvt_bf(lo[3]);
        a[4]=cvt_bf(hi[0]); a[5]=cvt_bf(hi[1]); a[6]=cvt_bf(hi[2]); a[7]=cvt_bf(hi[3]);
        const unsigned short* wp = lds_w + ((size_t)(kt * 4) * 64 + lane) * 8;
        a0 = MFMA(*(const short8*)(wp +    0), a, a0, 0,0,0);
        a1 = MFMA(*(const short8*)(wp +  512), a, a1, 0,0,0);
        a2 = MFMA(*(const short8*)(wp + 1024), a, a2, 0,0,0);
        a3 = MFMA(*(const short8*)(wp + 1536), a, a3, 0,0,0);
    }

    if (t > 0) {
        // ---- 4. single drain: sweep + prefetch have had ~xMFMA time ----
        asm volatile("s_waitcnt vmcnt(0)" ::: "memory");
        __builtin_amdgcn_sched_barrier(0);
        unsigned pend = 0;
        #pragma unroll
        for (int k = 0; k < 16; ++k)
            pend |= frag_ready(hfr[k]) ? 0u : (1u << k);
        #pragma unroll 1
        while (!__all(pend == 0)) {
            #pragma unroll
            for (int k = 0; k < 16; ++k)
                if (pend & (1u << k)) hfr[k] = load16_mall(hr + k * 32);
            asm volatile("s_waitcnt vmcnt(0)" ::: "memory");
            __builtin_amdgcn_sched_barrier(0);
            unsigned np = 0;
            #pragma unroll
            for (int k = 0; k < 16; ++k)
                if (pend & (1u << k))
                    np |= frag_ready(hfr[k]) ? 0u : (1u << k);
            pend = np;
        }
        __builtin_amdgcn_sched_barrier(0);

        // ---- 5. h-part MFMA ----
        #pragma unroll
        for (int k = 0; k < 16; ++k) {
            const unsigned short* wp = lds_w + ((size_t)((8 + k) * 4) * 64 + lane) * 8;
            a0 = MFMA(*(const short8*)(wp +    0), hfr[k], a0, 0,0,0);
            a1 = MFMA(*(const short8*)(wp +  512), hfr[k], a1, 0,0,0);
            a2 = MFMA(*(const short8*)(wp + 1024), hfr[k], a2, 0,0,0);
            a3 = MFMA(*(const short8*)(wp + 1536), hfr[k], a3, 0,0,0);
        }
    } else {
        asm volatile("s_waitcnt vmcnt(0)" ::: "memory");   // t=0: settle prefetch path
        __builtin_amdgcn_sched_barrier(0);
    }

    // ---- 6. lane-local LSTM update; fire-and-forget stores ----
    unsigned short hu[4];
    #pragma unroll
    for (int j = 0; j < 4; ++j) {
        const float iv = a0[j] + bi[j];
        const float jv = a1[j] + bj[j];
        const float fv = a2[j] + bf_[j];
        const float ov = a3[j] + bo[j];
        const float cn = sigmoidf_(fv) * c_frag[j] + sigmoidf_(iv) * tanhf_(jv);
        c_frag[j] = cn;
        hu[j] = f2bf(sigmoidf_(ov) * tanhf_(cn));
    }
    uint2v pk;
    pk[0] = (unsigned)hu[0] | ((unsigned)hu[1] << 16);
    pk[1] = (unsigned)hu[2] | ((unsigned)hu[3] << 16);
    store8_mall(hbuf + (size_t)(t + 1) * BH + hsto_off, pk);
    if (t + PRE_AHEAD <= T_DIM) {     // re-arm own region of slot t+5
        const uint2v sentv = {SENT, SENT};
        store8_mall(hbuf + (size_t)(t + PRE_AHEAD) * BH + hsto_off, sentv);
    }
    // Write-once slots; arm(t+5) precedes data(t+4 end) in same-wave program
    // order on the same address -> in-order commit at the MALL. Consumer at
    // step u observed h_{u-1} (written after the arm of slot u) so its sweep
    // of slot u can never see pre-arm stale data.
}

// ---------------- LSTM persistent kernel ----------------
// 256 blocks, 1/CU (96 KiB LDS). bg = blk&7 (32 batch rows), hg = blk>>3
// (16 hidden cols). W staged once in LDS as W^T fragments; swapped MFMA
// (gates^T = W^T * in^T) -> lane owns 1 batch row x 4 consecutive cols.
// h: 257 write-once slots, sentinel-armed 5 steps ahead (R8-proven).
__global__ void __launch_bounds__(128, 1)
lstm_persist(const float* __restrict__ x,
             const float* __restrict__ wk,
             const float* __restrict__ bias,
             unsigned short* __restrict__ hbuf)   // [T+1][B][H] bf16
{
    extern __shared__ unsigned short lds_w[];     // [96 frag][64 lane][8]
    const int tid = threadIdx.x;
    const int blk = blockIdx.x;
    const int bg  = blk & 7;
    const int hg  = blk >> 3;
    const int bb  = bg * 32;
    const int hh  = hg * 16;

    // ---- preload weights into LDS as W^T fragments (once) ----
    // frag f=kt*4+g; lane l; elem j -> W[kt*32+(l>>4)*8+j][g*512+hh+(l&15)]
    for (int f = 0; f < 96; ++f) {
        const int kt = f >> 2, g = f & 3;
        for (int idx = tid; idx < 512; idx += 128) {
            const int c  = idx & 15;
            const int hi = (idx >> 4) & 3;
            const int j  = idx >> 6;
            const int k  = kt * 32 + hi * 8 + j;
            const int col = g * 512 + hh + c;
            lds_w[(f * 64 + hi * 16 + c) * 8 + j] = f2bf(wk[(size_t)k * 2048 + col]);
        }
    }
    __syncthreads();

    const int w    = tid >> 6;        // wave: batch rows [bb+w*16, +16)
    const int lane = tid & 63;
    const int lc   = lane & 15;
    const int lk   = lane >> 4;

    const f32x4 bi  = *(const f32x4*)(bias + 0 * 512 + hh + lk * 4);
    const f32x4 bj  = *(const f32x4*)(bias + 1 * 512 + hh + lk * 4);
    f32x4       bf_ = *(const f32x4*)(bias + 2 * 512 + hh + lk * 4);
    const f32x4 bo  = *(const f32x4*)(bias + 3 * 512 + hh + lk * 4);
    bf_ = bf_ + 1.0f;                                  // FORGET_BIAS

    f32x4 c_frag = {0.f, 0.f, 0.f, 0.f};

    const int arow = bb + w * 16 + lc;                 // batch row
    const float* xrow = x + (size_t)arow * E_DIM + lk * 8;
    const size_t hrow_off = (size_t)arow * H_DIM + lk * 8;      // read side
    const size_t hsto_off = (size_t)arow * H_DIM + hh + lk * 4; // write side

    // ---- preload x_0 into buffer A (compiler inserts the use-wait) ----
    f32x4 xA[16], xB[16];
    #pragma unroll
    for (int k = 0; k < 8; ++k) {
        xA[2 * k]     = *(const f32x4*)(xrow + k * 32);
        xA[2 * k + 1] = *(const f32x4*)(xrow + k * 32 + 4);
    }

    // ---- recurrence, 2 steps per iteration (static ping-pong, rule 20) ----
    for (int tb = 0; tb < T_DIM; tb += 2) {
        lstm_step(tb,     xA, xB, xrow, hbuf, hrow_off, hsto_off,
                  lds_w, lane, bi, bj, bf_, bo, c_frag);
        lstm_step(tb + 1, xB, xA, xrow, hbuf, hrow_off, hsto_off,
                  lds_w, lane, bi, bj, bf_, bo, c_frag);
    }
}

// ---------------- final projection: out = h_last @ W_out + b_out ----------------
__global__ void __launch_bounds__(256)
proj_gemm(const unsigned short* __restrict__ h,   // [256][512] bf16 (slot T)
          const float* __restrict__ wout,         // [512][V]
          const float* __restrict__ bout,         // [V]
          float* __restrict__ out)                // [256][V]
{
    const int tid  = threadIdx.x;
    const int w    = tid >> 6;
    const int lane = tid & 63;
    const int lc   = lane & 15;
    const int lk   = lane >> 4;
    const int n0   = blockIdx.x * 128 + w * 32;

    f32x4 acc[16][2];
    #pragma unroll
    for (int mt = 0; mt < 16; ++mt) {
        acc[mt][0] = (f32x4){0.f,0.f,0.f,0.f};
        acc[mt][1] = (f32x4){0.f,0.f,0.f,0.f};
    }
    int ncl[2];
    ncl[0] = min(n0 + lc,      V_DIM - 1);
    ncl[1] = min(n0 + 16 + lc, V_DIM - 1);

    #pragma unroll 4
    for (int kt = 0; kt < 16; ++kt) {
        short8 bfr[2];
        #pragma unroll
        for (int nt = 0; nt < 2; ++nt) {
            #pragma unroll
            for (int j = 0; j < 8; ++j) {
                const int k = kt * 32 + lk * 8 + j;
                bfr[nt][j] = (short)f2bf(wout[(size_t)k * V_DIM + ncl[nt]]);
            }
        }
        #pragma unroll
        for (int mt = 0; mt < 16; ++mt) {
            const short8 a = *(const short8*)(h + (size_t)(mt * 16 + lc) * H_DIM
                                                + kt * 32 + lk * 8);
            acc[mt][0] = MFMA(a, bfr[0], acc[mt][0], 0,0,0);
            acc[mt][1] = MFMA(a, bfr[1], acc[mt][1], 0,0,0);
        }
    }

    #pragma unroll
    for (int nt = 0; nt < 2; ++nt) {
        const int n = n0 + nt * 16 + lc;
        if (n < V_DIM) {
            const float bb = bout[n];
            #pragma unroll
            for (int mt = 0; mt < 16; ++mt)
                #pragma unroll
                for (int j = 0; j < 4; ++j)
                    out[(size_t)(mt * 16 + lk * 4 + j) * V_DIM + n] = acc[mt][nt][j] + bb;
        }
    }
}

extern "C" void kernel_launch(void* const* d_in, const int* in_sizes, int n_in,
                              void* d_out, int out_size, void* d_ws, size_t ws_size,
                              hipStream_t stream) {
    const float* x    = (const float*)d_in[0];
    const float* wk   = (const float*)d_in[1];
    const float* bias = (const float*)d_in[2];
    const float* wout = (const float*)d_in[3];
    const float* bout = (const float*)d_in[4];
    float* out = (float*)d_out;

    // hbuf: (T+1) slots of [B][H] bf16 ~= 64.3 MB (R7/R8-proven capacity)
    unsigned short* hbuf = (unsigned short*)d_ws;

    // Arm only slots 0..4 (1.3 MB); slots >=5 are re-armed just-in-time by
    // producers (step t arms slot t+5), wiping stale prior-replay data long
    // before any consumer can sweep it (R8-proven).
    hipMemsetAsync(hbuf, 0x7F, (size_t)PRE_AHEAD * BH * 2, stream);

    hipFuncSetAttribute((const void*)lstm_persist,
                        hipFuncAttributeMaxDynamicSharedMemorySize, 96 * 1024);

    hipLaunchKernelGGL(lstm_persist, dim3(256), dim3(128), 96 * 1024, stream,
                       x, wk, bias, hbuf);
    // h_last = slot T; kernel-end release + dispatch acquire hand it to proj.
    hipLaunchKernelGGL(proj_gemm, dim3((V_DIM + 127) / 128), dim3(256), 0, stream,
                       hbuf + (size_t)T_DIM * BH, wout, bout, out);
}

// Round 12
// 1767.529 us; speedup vs baseline: 1.1057x; 1.1057x over previous
//
#include <hip/hip_runtime.h>
#include <hip/hip_bf16.h>

#define T_DIM 256
#define B_DIM 256
#define E_DIM 256
#define H_DIM 512
#define V_DIM 50257
#define BH    (B_DIM * H_DIM)          // elems per h slot
#define RINGL 8                        // local (L2) ring slots
#define ARM_L 3                        // at step t, arm local slot t+3
#define PRE_AHEAD 5                    // at step t, arm MALL slot t+5
#define SENT  0x7F7F7F7Fu              // bf16 |h|<=1 can never be 0x7F7F

typedef __attribute__((ext_vector_type(8))) short short8;
typedef __attribute__((ext_vector_type(4))) float f32x4;
typedef __attribute__((ext_vector_type(4))) unsigned int uint4v;
typedef __attribute__((ext_vector_type(2))) unsigned int uint2v;

#define MFMA __builtin_amdgcn_mfma_f32_16x16x32_bf16

__device__ __forceinline__ unsigned short f2bf(float f) {
    union { float f; unsigned u; } v; v.f = f;
    unsigned r = v.u + 0x7FFFu + ((v.u >> 16) & 1u);
    return (unsigned short)(r >> 16);
}
__device__ __forceinline__ short cvt_bf(float f) { return (short)f2bf(f); }
__device__ __forceinline__ float sigmoidf_(float x) {
    return 1.0f / (1.0f + __expf(-x));
}
__device__ __forceinline__ float tanhf_(float x) {
    float xc = fminf(fmaxf(x, -15.0f), 15.0f);
    float e = __expf(2.0f * xc);
    return (e - 1.0f) / (e + 1.0f);
}

// Dual-path h exchange:
//  MALL path (sc0 sc1): placement-independent, always correct/late.
//  LOCAL path (plain store -> own XCD L2; sc0 load bypasses L1, reads L2):
//    used ONLY for producers verified co-XCD via the runtime XCC map.
//    Arm+data are same-address program-ordered in L2, so a local read sees
//    sentinel (not ready) or fresh data, never stale. Wrong/unknown mapping
//    degrades to MALL per fragment -> liveness and correctness never depend
//    on placement. Loads return in-flight; consume only after s_waitcnt +
//    sched_barrier(0) (rule 18).
__device__ __forceinline__ short8 load16_mall(const unsigned short* p) {
    short8 r;
    asm volatile("global_load_dwordx4 %0, %1, off sc0 sc1"
                 : "=v"(r) : "v"(p) : "memory");
    return r;
}
__device__ __forceinline__ short8 load16_loc(const unsigned short* p) {
    short8 r;
    asm volatile("global_load_dwordx4 %0, %1, off sc0"
                 : "=v"(r) : "v"(p) : "memory");
    return r;
}
__device__ __forceinline__ void store8_mall(unsigned short* p, uint2v v) {
    asm volatile("global_store_dwordx2 %0, %1, off sc0 sc1"
                 :: "v"(p), "v"(v) : "memory");
}
__device__ __forceinline__ void store8_loc(unsigned short* p, uint2v v) {
    asm volatile("global_store_dwordx2 %0, %1, off"
                 :: "v"(p), "v"(v) : "memory");
}
__device__ __forceinline__ int load_int_mall(const int* p) {
    int r;
    asm volatile("global_load_dword %0, %1, off sc0 sc1\n\t"
                 "s_waitcnt vmcnt(0)"
                 : "=v"(r) : "v"(p) : "memory");
    return r;
}
__device__ __forceinline__ void store_int_mall(int* p, int v) {
    asm volatile("global_store_dword %0, %1, off sc0 sc1"
                 :: "v"(p), "v"(v) : "memory");
}
__device__ __forceinline__ bool frag_ready(short8 v) {
    union { short8 s; uint4v u; } c; c.s = v;
    return (c.u[0] != SENT) & (c.u[1] != SENT) & (c.u[2] != SENT) & (c.u[3] != SENT);
}

// ---------------- LSTM persistent kernel ----------------
// R8 protocol + dual-path sweep. 256 blocks, 1/CU. bg = blk&7 (32 batch
// rows), hg = blk>>3 (16 hidden cols). W staged once in LDS as W^T frags;
// swapped MFMA -> lane owns 1 batch row x 4 consecutive hidden cols.
__global__ void __launch_bounds__(128, 1)
lstm_persist(const float* __restrict__ x,
             const float* __restrict__ wk,
             const float* __restrict__ bias,
             unsigned short* __restrict__ hbuf_m,   // [T+1][B][H] MALL copy
             unsigned short* __restrict__ hbuf_l,   // [RINGL][B][H] local copy
             int* __restrict__ xcctab)              // [8][32] xcc ids, 64B stride
{
    extern __shared__ unsigned short lds_w[];       // [96 frag][64 lane][8]
    const int tid = threadIdx.x;
    const int blk = blockIdx.x;
    const int bg  = blk & 7;
    const int hg  = blk >> 3;
    const int bb  = bg * 32;
    const int hh  = hg * 16;

    // ---- publish my XCD id (once, before the long weight preload) ----
    unsigned xcc;
    asm volatile("s_getreg_b32 %0, hwreg(HW_REG_XCC_ID)" : "=s"(xcc));
    if (tid == 0)
        store_int_mall(xcctab + bg * 512 + hg * 16, (int)(xcc & 7u));

    // ---- preload weights into LDS as W^T fragments (once) ----
    // frag f=kt*4+g; lane l; elem j -> W[kt*32+(l>>4)*8+j][g*512+hh+(l&15)]
    for (int f = 0; f < 96; ++f) {
        const int kt = f >> 2, g = f & 3;
        for (int idx = tid; idx < 512; idx += 128) {
            const int c  = idx & 15;
            const int hi = (idx >> 4) & 3;
            const int j  = idx >> 6;
            const int k  = kt * 32 + hi * 8 + j;
            const int col = g * 512 + hh + c;
            lds_w[(f * 64 + hi * 16 + c) * 8 + j] = f2bf(wk[(size_t)k * 2048 + col]);
        }
    }
    __syncthreads();

    const int w    = tid >> 6;        // wave: batch rows [bb+w*16, +16)
    const int lane = tid & 63;
    const int lc   = lane & 15;
    const int lk   = lane >> 4;

    // ---- build per-fragment locality mask (bounded best-effort) ----
    // frag k (h cols [32k,32k+32)) is produced by hg = 2k, 2k+1.
    unsigned fragmask = 0;
    {
        const int* tp = xcctab + bg * 512 + (lane & 31) * 16;
        int e = -1;
        #pragma unroll 1
        for (int it = 0; it < 256; ++it) {
            e = load_int_mall(tp);
            if (__all(e != -1)) break;
            __builtin_amdgcn_s_sleep(8);
        }
        if (__all(e != -1)) {
            const int p0 = __shfl(e, 2 * (lane & 15));
            const int p1 = __shfl(e, 2 * (lane & 15) + 1);
            const bool loc = (p0 == (int)(xcc & 7u)) && (p1 == (int)(xcc & 7u));
            fragmask = (unsigned)(__ballot(loc) & 0xFFFFull);
        }
        // fragmask == 0 -> pure-MALL (R8 behavior), always correct.
    }

    const f32x4 bi  = *(const f32x4*)(bias + 0 * 512 + hh + lk * 4);
    const f32x4 bj  = *(const f32x4*)(bias + 1 * 512 + hh + lk * 4);
    f32x4       bf_ = *(const f32x4*)(bias + 2 * 512 + hh + lk * 4);
    const f32x4 bo  = *(const f32x4*)(bias + 3 * 512 + hh + lk * 4);
    bf_ = bf_ + 1.0f;                                  // FORGET_BIAS

    f32x4 c_frag = {0.f, 0.f, 0.f, 0.f};

    const int arow = bb + w * 16 + lc;                 // batch row
    const float* xrow = x + (size_t)arow * E_DIM + lk * 8;
    const size_t hrow_off = (size_t)arow * H_DIM + lk * 8;      // read side
    const size_t hsto_off = (size_t)arow * H_DIM + hh + lk * 4; // write side

    // ---- x_0 prefetch into regs ----
    f32x4 xreg[16];
    #pragma unroll
    for (int k = 0; k < 8; ++k) {
        xreg[2 * k]     = *(const f32x4*)(xrow + k * 32);
        xreg[2 * k + 1] = *(const f32x4*)(xrow + k * 32 + 4);
    }

    const uint2v sentv = {SENT, SENT};

    for (int t = 0; t < T_DIM; ++t) {
        // ---- 1. x-part MFMA from resident regs (R8 order) ----
        f32x4 a0 = {0.f,0.f,0.f,0.f}, a1 = a0, a2 = a0, a3 = a0;
        short8 apk[8];
        #pragma unroll
        for (int kt = 0; kt < 8; ++kt) {
            const f32x4 lo = xreg[2 * kt];
            const f32x4 hi = xreg[2 * kt + 1];
            short8 a;
            a[0]=cvt_bf(lo[0]); a[1]=cvt_bf(lo[1]); a[2]=cvt_bf(lo[2]); a[3]=cvt_bf(lo[3]);
            a[4]=cvt_bf(hi[0]); a[5]=cvt_bf(hi[1]); a[6]=cvt_bf(hi[2]); a[7]=cvt_bf(hi[3]);
            apk[kt] = a;
        }
        #pragma unroll
        for (int kt = 0; kt < 8; ++kt) {
            const unsigned short* wp = lds_w + ((size_t)(kt * 4) * 64 + lane) * 8;
            a0 = MFMA(*(const short8*)(wp +    0), apk[kt], a0, 0,0,0);
            a1 = MFMA(*(const short8*)(wp +  512), apk[kt], a1, 0,0,0);
            a2 = MFMA(*(const short8*)(wp + 1024), apk[kt], a2, 0,0,0);
            a3 = MFMA(*(const short8*)(wp + 1536), apk[kt], a3, 0,0,0);
        }

        // ---- 2. next-step x prefetch (C++ cached loads; L2-shared by bg) ----
        if (t + 1 < T_DIM) {
            const float* xn = xrow + (size_t)(t + 1) * (B_DIM * E_DIM);
            #pragma unroll
            for (int k = 0; k < 8; ++k) {
                xreg[2 * k]     = *(const f32x4*)(xn + k * 32);
                xreg[2 * k + 1] = *(const f32x4*)(xn + k * 32 + 4);
            }
        }

        if (t > 0) {
            // ---- 3. dual-path sweep of h_t (issued late = sampled late) ----
            const unsigned short* hr_l = hbuf_l + (size_t)(t & (RINGL - 1)) * BH + hrow_off;
            const unsigned short* hr_m = hbuf_m + (size_t)t * BH + hrow_off;
            short8 hfr[16];
            #pragma unroll
            for (int k = 0; k < 16; ++k) {
                if ((fragmask >> k) & 1) hfr[k] = load16_loc(hr_l + k * 32);
                else                     hfr[k] = load16_mall(hr_m + k * 32);
            }
            asm volatile("s_waitcnt vmcnt(0)" ::: "memory");
            __builtin_amdgcn_sched_barrier(0);

            unsigned pend = 0;
            #pragma unroll
            for (int k = 0; k < 16; ++k)
                pend |= frag_ready(hfr[k]) ? 0u : (1u << k);
            int round = 0;
            #pragma unroll 1
            while (!__all(pend == 0)) {
                #pragma unroll
                for (int k = 0; k < 16; ++k)
                    if (pend & (1u << k)) {
                        if (round == 0 && ((fragmask >> k) & 1))
                            hfr[k] = load16_loc(hr_l + k * 32);   // one local retry
                        else
                            hfr[k] = load16_mall(hr_m + k * 32);  // escalate: MALL
                    }
                asm volatile("s_waitcnt vmcnt(0)" ::: "memory");
                __builtin_amdgcn_sched_barrier(0);
                unsigned np = 0;
                #pragma unroll
                for (int k = 0; k < 16; ++k)
                    if (pend & (1u << k))
                        np |= frag_ready(hfr[k]) ? 0u : (1u << k);
                pend = np;
                ++round;
            }
            __builtin_amdgcn_sched_barrier(0);

            // ---- 4. h-part MFMA ----
            #pragma unroll
            for (int k = 0; k < 16; ++k) {
                const unsigned short* wp = lds_w + ((size_t)((8 + k) * 4) * 64 + lane) * 8;
                a0 = MFMA(*(const short8*)(wp +    0), hfr[k], a0, 0,0,0);
                a1 = MFMA(*(const short8*)(wp +  512), hfr[k], a1, 0,0,0);
                a2 = MFMA(*(const short8*)(wp + 1024), hfr[k], a2, 0,0,0);
                a3 = MFMA(*(const short8*)(wp + 1536), hfr[k], a3, 0,0,0);
            }
        }

        // ---- 5. lane-local LSTM update; fire-and-forget double-publish ----
        unsigned short hu[4];
        #pragma unroll
        for (int j = 0; j < 4; ++j) {
            const float iv = a0[j] + bi[j];
            const float jv = a1[j] + bj[j];
            const float fv = a2[j] + bf_[j];
            const float ov = a3[j] + bo[j];
            const float cn = sigmoidf_(fv) * c_frag[j] + sigmoidf_(iv) * tanhf_(jv);
            c_frag[j] = cn;
            hu[j] = f2bf(sigmoidf_(ov) * tanhf_(cn));
        }
        uint2v pk;
        pk[0] = (unsigned)hu[0] | ((unsigned)hu[1] << 16);
        pk[1] = (unsigned)hu[2] | ((unsigned)hu[3] << 16);
        store8_loc (hbuf_l + (size_t)((t + 1) & (RINGL - 1)) * BH + hsto_off, pk);
        store8_mall(hbuf_m + (size_t)(t + 1) * BH + hsto_off, pk);
        if (t + ARM_L < T_DIM)        // arm local ring slot of h_{t+3}
            store8_loc(hbuf_l + (size_t)((t + ARM_L) & (RINGL - 1)) * BH + hsto_off, sentv);
        if (t + PRE_AHEAD <= T_DIM)   // arm MALL slot t+5 (R8 protocol)
            store8_mall(hbuf_m + (size_t)(t + PRE_AHEAD) * BH + hsto_off, sentv);
        // Local ring safety: armer at t implies bg-mates >= t-1, so readers
        // of the old occupant h_{t-5} (at step t-5) are long done; arm(t) ->
        // data(end of t+2) is same-wave same-address program order.
    }
}

// ---------------- final projection: out = h_last @ W_out + b_out ----------------
__global__ void __launch_bounds__(256)
proj_gemm(const unsigned short* __restrict__ h,   // [256][512] bf16 (MALL slot T)
          const float* __restrict__ wout,         // [512][V]
          const float* __restrict__ bout,         // [V]
          float* __restrict__ out)                // [256][V]
{
    const int tid  = threadIdx.x;
    const int w    = tid >> 6;
    const int lane = tid & 63;
    const int lc   = lane & 15;
    const int lk   = lane >> 4;
    const int n0   = blockIdx.x * 128 + w * 32;

    f32x4 acc[16][2];
    #pragma unroll
    for (int mt = 0; mt < 16; ++mt) {
        acc[mt][0] = (f32x4){0.f,0.f,0.f,0.f};
        acc[mt][1] = (f32x4){0.f,0.f,0.f,0.f};
    }
    int ncl[2];
    ncl[0] = min(n0 + lc,      V_DIM - 1);
    ncl[1] = min(n0 + 16 + lc, V_DIM - 1);

    #pragma unroll 4
    for (int kt = 0; kt < 16; ++kt) {
        short8 bfr[2];
        #pragma unroll
        for (int nt = 0; nt < 2; ++nt) {
            #pragma unroll
            for (int j = 0; j < 8; ++j) {
                const int k = kt * 32 + lk * 8 + j;
                bfr[nt][j] = (short)f2bf(wout[(size_t)k * V_DIM + ncl[nt]]);
            }
        }
        #pragma unroll
        for (int mt = 0; mt < 16; ++mt) {
            const short8 a = *(const short8*)(h + (size_t)(mt * 16 + lc) * H_DIM
                                                + kt * 32 + lk * 8);
            acc[mt][0] = MFMA(a, bfr[0], acc[mt][0], 0,0,0);
            acc[mt][1] = MFMA(a, bfr[1], acc[mt][1], 0,0,0);
        }
    }

    #pragma unroll
    for (int nt = 0; nt < 2; ++nt) {
        const int n = n0 + nt * 16 + lc;
        if (n < V_DIM) {
            const float bb = bout[n];
            #pragma unroll
            for (int mt = 0; mt < 16; ++mt)
                #pragma unroll
                for (int j = 0; j < 4; ++j)
                    out[(size_t)(mt * 16 + lk * 4 + j) * V_DIM + n] = acc[mt][nt][j] + bb;
        }
    }
}

extern "C" void kernel_launch(void* const* d_in, const int* in_sizes, int n_in,
                              void* d_out, int out_size, void* d_ws, size_t ws_size,
                              hipStream_t stream) {
    const float* x    = (const float*)d_in[0];
    const float* wk   = (const float*)d_in[1];
    const float* bias = (const float*)d_in[2];
    const float* wout = (const float*)d_in[3];
    const float* bout = (const float*)d_in[4];
    float* out = (float*)d_out;

    // ws layout: hbuf_m 257*256KiB ~= 64.3MB | hbuf_l 8*256KiB = 2MB | tab 16KB
    unsigned short* hbuf_m = (unsigned short*)d_ws;
    unsigned short* hbuf_l = (unsigned short*)((char*)d_ws + (size_t)(T_DIM + 1) * BH * 2);
    int*            xcctab = (int*)((char*)hbuf_l + (size_t)RINGL * BH * 2);

    // Per call (graph-replay safe): arm MALL slots 0..4, arm the whole local
    // ring (wipes prior-replay h), invalidate the xcc table.
    hipMemsetAsync(hbuf_m, 0x7F, (size_t)PRE_AHEAD * BH * 2, stream);
    hipMemsetAsync(hbuf_l, 0x7F, (size_t)RINGL * BH * 2, stream);
    hipMemsetAsync(xcctab, 0xFF, 8 * 32 * 16 * sizeof(int), stream);

    hipFuncSetAttribute((const void*)lstm_persist,
                        hipFuncAttributeMaxDynamicSharedMemorySize, 96 * 1024);

    hipLaunchKernelGGL(lstm_persist, dim3(256), dim3(128), 96 * 1024, stream,
                       x, wk, bias, hbuf_m, hbuf_l, xcctab);
    // h_last = MALL slot T; kernel-end release + dispatch acquire hand it off.
    hipLaunchKernelGGL(proj_gemm, dim3((V_DIM + 127) / 128), dim3(256), 0, stream,
                       hbuf_m + (size_t)T_DIM * BH, wout, bout, out);
}